// Round 2
// baseline (128.957 us; speedup 1.0000x reference)
//
#include <hip/hip_runtime.h>

// CNN encoder as implicit-im2col GEMM:
//   A(M=32*2040, K=1024) x Wp(K=1024, N=256), Wp[fd][k] = filt[fd]*W_k[fd][k]
//   out = relu(A*Wp + b_k)
// Round 10: barrier-free K-loop. R9's counted-vmcnt restructure was neutral
// (all pipes <35% busy -> lockstep-bound, not drain-bound). B is only 512 KB
// and L2-resident, so it is now served global->register directly:
//   - prep kernel re-tiles Wp into per-lane MFMA fragment order, so one
//     b-frag pair = one coalesced 1 KB global_load_dwordx4 per wave
//   - sB, global_load_lds, and ALL in-loop barriers deleted; sA is read-only
//     after a single prologue __syncthreads. 16 waves/CU free-run and
//     self-stagger, overlapping MFMA / LDS-read / L2-load pipes.
//   - B loads ping-pong software-pipelined (static names, unroll-2 body)
//   - setprio(1) around MFMA cluster (waves now phase-diverse -> T5 applies)

#define L_SZ   2048
#define NWIN   2040   // L - F (reference uses L - F)
#define BM     128
#define MT     16

typedef __attribute__((ext_vector_type(8)))  short bf16x8;
typedef __attribute__((ext_vector_type(4)))  short bf16x4;
typedef __attribute__((ext_vector_type(16))) float f32x16;

static __device__ __forceinline__ short f2bf(float f) {
    union { float f; unsigned u; } v; v.f = f;
    unsigned r = v.u + 0x7FFFu + ((v.u >> 16) & 1u);
    return (short)(r >> 16);
}

// ---- prep: wp3[c][nb][c8][l32][8 shorts], 32768 slots of 16 B = 512 KB.
// Slot (c, nb, c8, l32) holds Wp[c*32 + c8*8 + jj][nb*32 + l32], jj=0..7,
// with Wp[k][n] = Wk[k][n]*filt[k]. This is exactly the 32x32x16 bf16 MFMA
// B-fragment order: a wave's b[ks][j] is ONE contiguous 1 KB dwordx4 read
// (lanes 0..31 -> c8=2ks (k-half 0), lanes 32..63 -> c8=2ks+1 (k-half 1)).
__global__ __launch_bounds__(256) void prep_w_kernel(
    const float* __restrict__ Wk, const float* __restrict__ filt,
    short* __restrict__ wp3)
{
    int g   = blockIdx.x * 256 + threadIdx.x;  // 32768 slots
    int c   = g >> 10;          // K-chunk 0..31
    int nb  = (g >> 7) & 7;     // 32-col block 0..7
    int c8  = (g >> 5) & 3;     // 8-k subgroup 0..3
    int l32 = g & 31;
    int np  = nb * 32 + l32;
    int kb  = c * 32 + c8 * 8;
    bf16x8 o;
    #pragma unroll
    for (int jj = 0; jj < 8; ++jj)
        o[jj] = f2bf(Wk[(size_t)(kb + jj) * 256 + np] * filt[kb + jj]);
    *reinterpret_cast<bf16x8*>(&wp3[(size_t)g * 8]) = o;
}

__global__ __launch_bounds__(512, 4) void cnn_enc_kernel(
    const float* __restrict__ ub, const short* __restrict__ wp3,
    const float* __restrict__ bk, float* __restrict__ out)
{
    // A slab: 135 rows x 128 d bf16, stride 136 (32-row a-frag b128 reads
    // land 8 accesses/bank = balanced). Only LDS user now: 36720 B.
    __shared__ short sA[135 * 136];

    const int tid   = threadIdx.x;
    const int bid   = blockIdx.x;
    const int mt    = bid & 15;          // M-tile
    const int batch = bid >> 4;          // 0..31
    const int l0    = mt * BM;

    const int lane = tid & 63;
    const int wave = tid >> 6;     // 0..7
    const int wm   = wave >> 2;    // 0..1  (64-row sub-tile)
    const int wn   = wave & 3;     // 0..3  (64-col sub-tile)
    const int l32  = lane & 31;
    const int half = lane >> 5;    // 0..1

    // ---- prologue: stage all of A (split load / convert+write) ----------
    const float* ubb = ub + ((size_t)batch << 18);  // batch*2048*128
    float4 av[9];                                    // 4320 float4 / 512 thr
    #pragma unroll
    for (int u = 0; u < 9; ++u) {
        int idx = tid + u * 512;
        if (u < 8 || idx < 4320) {
            int r  = idx >> 5;             // row 0..134
            int c4 = idx & 31;             // float4 within row
            int rg = l0 + r; if (rg > L_SZ - 1) rg = L_SZ - 1;
            av[u] = *reinterpret_cast<const float4*>(
                ubb + ((size_t)rg << 7) + c4 * 4);
        }
    }
    #pragma unroll
    for (int u = 0; u < 9; ++u) {
        int idx = tid + u * 512;
        if (u < 8 || idx < 4320) {
            int r  = idx >> 5;
            int c4 = idx & 31;
            bf16x4 o;
            o.x = f2bf(av[u].x); o.y = f2bf(av[u].y);
            o.z = f2bf(av[u].z); o.w = f2bf(av[u].w);
            *reinterpret_cast<bf16x4*>(&sA[r * 136 + c4 * 4]) = o;
        }
    }

    f32x16 acc[2][2];
    #pragma unroll
    for (int i = 0; i < 2; ++i)
        #pragma unroll
        for (int j = 0; j < 2; ++j)
            acc[i][j] = (f32x16){0.f,0.f,0.f,0.f,0.f,0.f,0.f,0.f,
                                 0.f,0.f,0.f,0.f,0.f,0.f,0.f,0.f};

    // a-frag base offsets (shorts): row = wm*64 + i*32 + l32 (+f later),
    // d = ds*32 + ks*16 + half*8
    int aoff[2];
    #pragma unroll
    for (int i = 0; i < 2; ++i)
        aoff[i] = (wm * 64 + i * 32 + l32) * 136 + half * 8;

    // b-frag source: wb + c*8192 + j*1024 + ks*512 (shorts), one dwordx4/lane
    const short* wb = wp3 + (size_t)(wn * 2) * 1024 + (size_t)lane * 8;
    auto loadB = [&](bf16x8 (&b)[2][2], int c) {
        #pragma unroll
        for (int ks = 0; ks < 2; ++ks)
            #pragma unroll
            for (int j = 0; j < 2; ++j)
                b[ks][j] = *reinterpret_cast<const bf16x8*>(
                    wb + (size_t)c * 8192 + j * 1024 + ks * 512);
    };

    auto kstep = [&](int c, bf16x8 (&b)[2][2]) {
        const int f = c >> 2, ds = c & 3;
        bf16x8 a[2][2];                             // [ks][i]
        #pragma unroll
        for (int ks = 0; ks < 2; ++ks)
            #pragma unroll
            for (int i = 0; i < 2; ++i)
                a[ks][i] = *reinterpret_cast<const bf16x8*>(
                    &sA[aoff[i] + f * 136 + ds * 32 + ks * 16]);
        __builtin_amdgcn_s_setprio(1);
        #pragma unroll
        for (int ks = 0; ks < 2; ++ks)
            #pragma unroll
            for (int i = 0; i < 2; ++i)
                #pragma unroll
                for (int j = 0; j < 2; ++j)
                    acc[i][j] = __builtin_amdgcn_mfma_f32_32x32x16_bf16(
                        a[ks][i], b[ks][j], acc[i][j], 0, 0, 0);
        __builtin_amdgcn_s_setprio(0);
    };

    bf16x8 bA[2][2], bB[2][2];
    loadB(bA, 0);                 // lands while waves sit at the barrier
    __syncthreads();              // the ONLY barrier: sA visible, then free-run

    #pragma unroll 1
    for (int c = 0; c < 32; c += 2) {
        loadB(bB, c + 1);         // prefetch distance ~1 half-iter
        kstep(c, bA);
        if (c < 30) loadB(bA, c + 2);
        kstep(c + 1, bB);
    }

    // ---- epilogue: bias + relu, streaming stores
    // C/D 32x32: col = lane&31, row = (reg&3) + 8*(reg>>2) + 4*(lane>>5)
    #pragma unroll
    for (int j = 0; j < 2; ++j) {
        int n_glob = wn * 64 + j * 32 + l32;
        float bias = bk[n_glob];
        #pragma unroll
        for (int i = 0; i < 2; ++i) {
            #pragma unroll
            for (int r = 0; r < 16; ++r) {
                int row = (r & 3) + 8 * (r >> 2) + 4 * half;
                int l = l0 + wm * 64 + i * 32 + row;
                if (l < NWIN) {
                    float v = acc[i][j][r] + bias;
                    __builtin_nontemporal_store(
                        v > 0.f ? v : 0.f,
                        &out[((size_t)batch * NWIN + l) * 256 + n_glob]);
                }
            }
        }
    }
}

extern "C" void kernel_launch(void* const* d_in, const int* in_sizes, int n_in,
                              void* d_out, int out_size, void* d_ws, size_t ws_size,
                              hipStream_t stream) {
    const float* ub   = (const float*)d_in[0];  // (32,2048,128) fp32
    const float* filt = (const float*)d_in[1];  // (8,128) fp32
    const float* Wk   = (const float*)d_in[2];  // (1024,256) fp32
    const float* bk   = (const float*)d_in[3];  // (256,) fp32
    float* out = (float*)d_out;                 // (32,2040,256) fp32
    short* wp3 = (short*)d_ws;                  // 512 KB fragment-order Wp

    hipLaunchKernelGGL(prep_w_kernel, dim3(128), dim3(256), 0, stream,
                       Wk, filt, wp3);
    hipLaunchKernelGGL(cnn_enc_kernel, dim3(32 * MT), dim3(512), 0, stream,
                       ub, wp3, bk, out);
}

// Round 3
// 126.274 us; speedup vs baseline: 1.0213x; 1.0213x over previous
//
#include <hip/hip_runtime.h>

// CNN encoder as implicit-im2col GEMM:
//   A(M=32*2040, K=1024) x Wp(K=1024, N=256), Wp[fd][k] = filt[fd]*W_k[fd][k]
//   out = relu(A*Wp + b_k)
// Round 11: R10 structure (barrier-free, B global->reg from L2, sA read-only
// after one prologue barrier) but the K-loop is FULLY UNROLLED. R10's pipe
// utilizations (26% MFMA + 19% LDS + 29% L2 + 12% VALU ~= 86%) summed like
// serial phases: with `unroll 1` the scheduler could not interleave iter c's
// MFMAs with iter c+1's loads, so each wave serialized load->wait->MFMA and
// 4 waves/SIMD couldn't cover it. Full unroll gives the compiler the whole
// straight-line body: loads hoisted across ksteps, counted waitcnts, a-frag
// addresses folded to ds_read immediates. launch_bounds(512,4) still caps
// VGPR+AGPR at 128 so hoisting cannot drop occupancy.

#define L_SZ   2048
#define NWIN   2040   // L - F (reference uses L - F)
#define BM     128
#define MT     16

typedef __attribute__((ext_vector_type(8)))  short bf16x8;
typedef __attribute__((ext_vector_type(4)))  short bf16x4;
typedef __attribute__((ext_vector_type(16))) float f32x16;

static __device__ __forceinline__ short f2bf(float f) {
    union { float f; unsigned u; } v; v.f = f;
    unsigned r = v.u + 0x7FFFu + ((v.u >> 16) & 1u);
    return (short)(r >> 16);
}

// ---- prep: wp3[c][nb][c8][l32][8 shorts], 32768 slots of 16 B = 512 KB.
// Slot (c, nb, c8, l32) holds Wp[c*32 + c8*8 + jj][nb*32 + l32], jj=0..7,
// with Wp[k][n] = Wk[k][n]*filt[k]. This is exactly the 32x32x16 bf16 MFMA
// B-fragment order: a wave's b[ks][j] is ONE contiguous 1 KB dwordx4 read
// (lanes 0..31 -> c8=2ks (k-half 0), lanes 32..63 -> c8=2ks+1 (k-half 1)).
__global__ __launch_bounds__(256) void prep_w_kernel(
    const float* __restrict__ Wk, const float* __restrict__ filt,
    short* __restrict__ wp3)
{
    int g   = blockIdx.x * 256 + threadIdx.x;  // 32768 slots
    int c   = g >> 10;          // K-chunk 0..31
    int nb  = (g >> 7) & 7;     // 32-col block 0..7
    int c8  = (g >> 5) & 3;     // 8-k subgroup 0..3
    int l32 = g & 31;
    int np  = nb * 32 + l32;
    int kb  = c * 32 + c8 * 8;
    bf16x8 o;
    #pragma unroll
    for (int jj = 0; jj < 8; ++jj)
        o[jj] = f2bf(Wk[(size_t)(kb + jj) * 256 + np] * filt[kb + jj]);
    *reinterpret_cast<bf16x8*>(&wp3[(size_t)g * 8]) = o;
}

__global__ __launch_bounds__(512, 4) void cnn_enc_kernel(
    const float* __restrict__ ub, const short* __restrict__ wp3,
    const float* __restrict__ bk, float* __restrict__ out)
{
    // A slab: 135 rows x 128 d bf16, stride 136 (32-row a-frag b128 reads
    // land 8 accesses/bank = balanced). Only LDS user now: 36720 B.
    __shared__ short sA[135 * 136];

    const int tid   = threadIdx.x;
    const int bid   = blockIdx.x;
    const int mt    = bid & 15;          // M-tile
    const int batch = bid >> 4;          // 0..31
    const int l0    = mt * BM;

    const int lane = tid & 63;
    const int wave = tid >> 6;     // 0..7
    const int wm   = wave >> 2;    // 0..1  (64-row sub-tile)
    const int wn   = wave & 3;     // 0..3  (64-col sub-tile)
    const int l32  = lane & 31;
    const int half = lane >> 5;    // 0..1

    // ---- prologue: stage all of A (split load / convert+write) ----------
    const float* ubb = ub + ((size_t)batch << 18);  // batch*2048*128
    float4 av[9];                                    // 4320 float4 / 512 thr
    #pragma unroll
    for (int u = 0; u < 9; ++u) {
        int idx = tid + u * 512;
        if (u < 8 || idx < 4320) {
            int r  = idx >> 5;             // row 0..134
            int c4 = idx & 31;             // float4 within row
            int rg = l0 + r; if (rg > L_SZ - 1) rg = L_SZ - 1;
            av[u] = *reinterpret_cast<const float4*>(
                ubb + ((size_t)rg << 7) + c4 * 4);
        }
    }
    #pragma unroll
    for (int u = 0; u < 9; ++u) {
        int idx = tid + u * 512;
        if (u < 8 || idx < 4320) {
            int r  = idx >> 5;
            int c4 = idx & 31;
            bf16x4 o;
            o.x = f2bf(av[u].x); o.y = f2bf(av[u].y);
            o.z = f2bf(av[u].z); o.w = f2bf(av[u].w);
            *reinterpret_cast<bf16x4*>(&sA[r * 136 + c4 * 4]) = o;
        }
    }

    f32x16 acc[2][2];
    #pragma unroll
    for (int i = 0; i < 2; ++i)
        #pragma unroll
        for (int j = 0; j < 2; ++j)
            acc[i][j] = (f32x16){0.f,0.f,0.f,0.f,0.f,0.f,0.f,0.f,
                                 0.f,0.f,0.f,0.f,0.f,0.f,0.f,0.f};

    // a-frag base offsets (shorts): row = wm*64 + i*32 + l32 (+f later),
    // d = ds*32 + ks*16 + half*8
    int aoff[2];
    #pragma unroll
    for (int i = 0; i < 2; ++i)
        aoff[i] = (wm * 64 + i * 32 + l32) * 136 + half * 8;

    // b-frag source: wb + c*8192 + j*1024 + ks*512 (shorts), one dwordx4/lane
    const short* wb = wp3 + (size_t)(wn * 2) * 1024 + (size_t)lane * 8;
    auto loadB = [&](bf16x8 (&b)[2][2], int c) {
        #pragma unroll
        for (int ks = 0; ks < 2; ++ks)
            #pragma unroll
            for (int j = 0; j < 2; ++j)
                b[ks][j] = *reinterpret_cast<const bf16x8*>(
                    wb + (size_t)c * 8192 + j * 1024 + ks * 512);
    };

    auto kstep = [&](int c, bf16x8 (&b)[2][2]) {
        const int f = c >> 2, ds = c & 3;
        bf16x8 a[2][2];                             // [ks][i]
        #pragma unroll
        for (int ks = 0; ks < 2; ++ks)
            #pragma unroll
            for (int i = 0; i < 2; ++i)
                a[ks][i] = *reinterpret_cast<const bf16x8*>(
                    &sA[aoff[i] + f * 136 + ds * 32 + ks * 16]);
        __builtin_amdgcn_s_setprio(1);
        #pragma unroll
        for (int ks = 0; ks < 2; ++ks)
            #pragma unroll
            for (int i = 0; i < 2; ++i)
                #pragma unroll
                for (int j = 0; j < 2; ++j)
                    acc[i][j] = __builtin_amdgcn_mfma_f32_32x32x16_bf16(
                        a[ks][i], b[ks][j], acc[i][j], 0, 0, 0);
        __builtin_amdgcn_s_setprio(0);
    };

    bf16x8 bA[2][2], bB[2][2];
    loadB(bA, 0);                 // lands while waves sit at the barrier
    __syncthreads();              // the ONLY barrier: sA visible, then free-run

    // FULL unroll: 16 straight-line ping-pong bodies; compiler schedules
    // loads/ds_reads/MFMAs across ksteps with counted waitcnts.
    #pragma unroll
    for (int c = 0; c < 32; c += 2) {
        loadB(bB, c + 1);
        kstep(c, bA);
        if (c < 30) loadB(bA, c + 2);
        kstep(c + 1, bB);
    }

    // ---- epilogue: bias + relu, streaming stores
    // C/D 32x32: col = lane&31, row = (reg&3) + 8*(reg>>2) + 4*(lane>>5)
    #pragma unroll
    for (int j = 0; j < 2; ++j) {
        int n_glob = wn * 64 + j * 32 + l32;
        float bias = bk[n_glob];
        #pragma unroll
        for (int i = 0; i < 2; ++i) {
            #pragma unroll
            for (int r = 0; r < 16; ++r) {
                int row = (r & 3) + 8 * (r >> 2) + 4 * half;
                int l = l0 + wm * 64 + i * 32 + row;
                if (l < NWIN) {
                    float v = acc[i][j][r] + bias;
                    __builtin_nontemporal_store(
                        v > 0.f ? v : 0.f,
                        &out[((size_t)batch * NWIN + l) * 256 + n_glob]);
                }
            }
        }
    }
}

extern "C" void kernel_launch(void* const* d_in, const int* in_sizes, int n_in,
                              void* d_out, int out_size, void* d_ws, size_t ws_size,
                              hipStream_t stream) {
    const float* ub   = (const float*)d_in[0];  // (32,2048,128) fp32
    const float* filt = (const float*)d_in[1];  // (8,128) fp32
    const float* Wk   = (const float*)d_in[2];  // (1024,256) fp32
    const float* bk   = (const float*)d_in[3];  // (256,) fp32
    float* out = (float*)d_out;                 // (32,2040,256) fp32
    short* wp3 = (short*)d_ws;                  // 512 KB fragment-order Wp

    hipLaunchKernelGGL(prep_w_kernel, dim3(128), dim3(256), 0, stream,
                       Wk, filt, wp3);
    hipLaunchKernelGGL(cnn_enc_kernel, dim3(32 * MT), dim3(512), 0, stream,
                       ub, wp3, bk, out);
}

// Round 4
// 120.236 us; speedup vs baseline: 1.0725x; 1.0502x over previous
//
#include <hip/hip_runtime.h>

// CNN encoder as implicit-im2col GEMM:
//   A(M=32*2040, K=1024) x Wp(K=1024, N=256), Wp[fd][k] = filt[fd]*W_k[fd][k]
//   out = relu(A*Wp + b_k)
// Round 12: arithmetic-intensity fix. R9-R11 showed sync/scheduling changes
// are all neutral: with 64x64 wave tiles, per-CU per-K-step demand is
// MFMA 1024 cyc ~= LDS 1024 ~= L2 1170 -> three pipes at parity, MfmaUtil
// pinned at ~26% (= 32.8k matrix cyc / 126k total, measured). This round
// doubles per-wave output to 128x64 (4x2 of 32x32): 16 MFMAs per K-step
// against the SAME 8 a-frag ds_reads and 4 b-frag L2 loads. New per-CU
// per-iter demand: MFMA 1024 / LDS 512 / L2 585 -> matrix pipe dominant.
//   - blocks: 256 thr, 4 waves (1M x 4N), BM=128, BN=256; 2 blocks/CU
//     (reg-limited), so prologue/epilogue phases overlap across blocks
//   - acc = 128 AGPR; __launch_bounds__(256,2) opens 256 regs/wave
//   - barrier-free K-loop, B global->reg from L2 (R10), ping-pong prefetch
//   - prologue A-stage in 3 register-capped groups (load 6 / convert 6)

#define L_SZ   2048
#define NWIN   2040   // L - F (reference uses L - F)
#define BM     128
#define MT     16

typedef __attribute__((ext_vector_type(8)))  short bf16x8;
typedef __attribute__((ext_vector_type(4)))  short bf16x4;
typedef __attribute__((ext_vector_type(16))) float f32x16;

static __device__ __forceinline__ short f2bf(float f) {
    union { float f; unsigned u; } v; v.f = f;
    unsigned r = v.u + 0x7FFFu + ((v.u >> 16) & 1u);
    return (short)(r >> 16);
}

// ---- prep: wp3[c][nb][c8][l32][8 shorts], 32768 slots of 16 B = 512 KB.
// Slot (c, nb, c8, l32) holds Wp[c*32 + c8*8 + jj][nb*32 + l32], jj=0..7,
// with Wp[k][n] = Wk[k][n]*filt[k]. This is exactly the 32x32x16 bf16 MFMA
// B-fragment order: a wave's b[ks][j] is ONE contiguous 1 KB dwordx4 read
// (lanes 0..31 -> c8=2ks (k-half 0), lanes 32..63 -> c8=2ks+1 (k-half 1)).
__global__ __launch_bounds__(256) void prep_w_kernel(
    const float* __restrict__ Wk, const float* __restrict__ filt,
    short* __restrict__ wp3)
{
    int g   = blockIdx.x * 256 + threadIdx.x;  // 32768 slots
    int c   = g >> 10;          // K-chunk 0..31
    int nb  = (g >> 7) & 7;     // 32-col block 0..7
    int c8  = (g >> 5) & 3;     // 8-k subgroup 0..3
    int l32 = g & 31;
    int np  = nb * 32 + l32;
    int kb  = c * 32 + c8 * 8;
    bf16x8 o;
    #pragma unroll
    for (int jj = 0; jj < 8; ++jj)
        o[jj] = f2bf(Wk[(size_t)(kb + jj) * 256 + np] * filt[kb + jj]);
    *reinterpret_cast<bf16x8*>(&wp3[(size_t)g * 8]) = o;
}

__global__ __launch_bounds__(256, 2) void cnn_enc_kernel(
    const float* __restrict__ ub, const short* __restrict__ wp3,
    const float* __restrict__ bk, float* __restrict__ out)
{
    // A slab: 135 rows x 128 d bf16, stride 136 (32-row a-frag b128 reads
    // land 8 accesses/bank = balanced). 36720 B; 2 blocks/CU -> 73.4 KB.
    __shared__ short sA[135 * 136];

    const int tid   = threadIdx.x;
    const int bid   = blockIdx.x;
    const int mt    = bid & 15;          // M-tile
    const int batch = bid >> 4;          // 0..31
    const int l0    = mt * BM;

    const int lane = tid & 63;
    const int wave = tid >> 6;     // 0..3
    const int wn   = wave;         // 64-col sub-tile; rows: all 128
    const int l32  = lane & 31;
    const int half = lane >> 5;    // 0..1

    // ---- prologue: stage all of A, 3 register-capped groups --------------
    // 4320 float4 units / 256 thr = 17 per thread (last partial).
    const float* ubb = ub + ((size_t)batch << 18);  // batch*2048*128
    auto stageGroup = [&](int u0, int u1) {
        float4 av[6];
        #pragma unroll
        for (int u = u0; u < u1; ++u) {
            int idx = tid + u * 256;
            if (u < 16 || idx < 4320) {
                int r  = idx >> 5;             // row 0..134
                int c4 = idx & 31;             // float4 within row
                int rg = l0 + r; if (rg > L_SZ - 1) rg = L_SZ - 1;
                av[u - u0] = *reinterpret_cast<const float4*>(
                    ubb + ((size_t)rg << 7) + c4 * 4);
            }
        }
        #pragma unroll
        for (int u = u0; u < u1; ++u) {
            int idx = tid + u * 256;
            if (u < 16 || idx < 4320) {
                int r  = idx >> 5;
                int c4 = idx & 31;
                float4 v = av[u - u0];
                bf16x4 o;
                o.x = f2bf(v.x); o.y = f2bf(v.y);
                o.z = f2bf(v.z); o.w = f2bf(v.w);
                *reinterpret_cast<bf16x4*>(&sA[r * 136 + c4 * 4]) = o;
            }
        }
    };
    stageGroup(0, 6);
    stageGroup(6, 12);
    stageGroup(12, 17);

    f32x16 acc[4][2];
    #pragma unroll
    for (int i = 0; i < 4; ++i)
        #pragma unroll
        for (int j = 0; j < 2; ++j)
            acc[i][j] = (f32x16){0.f,0.f,0.f,0.f,0.f,0.f,0.f,0.f,
                                 0.f,0.f,0.f,0.f,0.f,0.f,0.f,0.f};

    // a-frag base offsets (shorts): row = i*32 + l32 (+f later),
    // d = ds*32 + ks*16 + half*8
    int aoff[4];
    #pragma unroll
    for (int i = 0; i < 4; ++i)
        aoff[i] = (i * 32 + l32) * 136 + half * 8;

    // b-frag source: wb + c*8192 + j*1024 + ks*512 (shorts), one dwordx4/lane
    const short* wb = wp3 + (size_t)(wn * 2) * 1024 + (size_t)lane * 8;
    auto loadB = [&](bf16x8 (&b)[2][2], int c) {
        #pragma unroll
        for (int ks = 0; ks < 2; ++ks)
            #pragma unroll
            for (int j = 0; j < 2; ++j)
                b[ks][j] = *reinterpret_cast<const bf16x8*>(
                    wb + (size_t)c * 8192 + j * 1024 + ks * 512);
    };

    auto kstep = [&](int c, bf16x8 (&b)[2][2]) {
        const int f = c >> 2, ds = c & 3;
        bf16x8 a[2][4];                             // [ks][i]
        #pragma unroll
        for (int ks = 0; ks < 2; ++ks)
            #pragma unroll
            for (int i = 0; i < 4; ++i)
                a[ks][i] = *reinterpret_cast<const bf16x8*>(
                    &sA[aoff[i] + f * 136 + ds * 32 + ks * 16]);
        __builtin_amdgcn_s_setprio(1);
        #pragma unroll
        for (int ks = 0; ks < 2; ++ks)
            #pragma unroll
            for (int i = 0; i < 4; ++i)
                #pragma unroll
                for (int j = 0; j < 2; ++j)
                    acc[i][j] = __builtin_amdgcn_mfma_f32_32x32x16_bf16(
                        a[ks][i], b[ks][j], acc[i][j], 0, 0, 0);
        __builtin_amdgcn_s_setprio(0);
    };

    bf16x8 bA[2][2], bB[2][2];
    loadB(bA, 0);                 // lands while waves sit at the barrier
    __syncthreads();              // the ONLY barrier: sA visible, then free-run

    #pragma unroll 1
    for (int c = 0; c < 32; c += 2) {
        loadB(bB, c + 1);         // prefetch distance ~1 half-iter
        kstep(c, bA);
        if (c < 30) loadB(bA, c + 2);
        kstep(c + 1, bB);
    }

    // ---- epilogue: bias + relu, streaming stores
    // C/D 32x32: col = lane&31, row = (reg&3) + 8*(reg>>2) + 4*(lane>>5)
    #pragma unroll
    for (int j = 0; j < 2; ++j) {
        int n_glob = wn * 64 + j * 32 + l32;
        float bias = bk[n_glob];
        #pragma unroll
        for (int i = 0; i < 4; ++i) {
            #pragma unroll
            for (int r = 0; r < 16; ++r) {
                int row = (r & 3) + 8 * (r >> 2) + 4 * half;
                int l = l0 + i * 32 + row;
                if (l < NWIN) {
                    float v = acc[i][j][r] + bias;
                    __builtin_nontemporal_store(
                        v > 0.f ? v : 0.f,
                        &out[((size_t)batch * NWIN + l) * 256 + n_glob]);
                }
            }
        }
    }
}

extern "C" void kernel_launch(void* const* d_in, const int* in_sizes, int n_in,
                              void* d_out, int out_size, void* d_ws, size_t ws_size,
                              hipStream_t stream) {
    const float* ub   = (const float*)d_in[0];  // (32,2048,128) fp32
    const float* filt = (const float*)d_in[1];  // (8,128) fp32
    const float* Wk   = (const float*)d_in[2];  // (1024,256) fp32
    const float* bk   = (const float*)d_in[3];  // (256,) fp32
    float* out = (float*)d_out;                 // (32,2040,256) fp32
    short* wp3 = (short*)d_ws;                  // 512 KB fragment-order Wp

    hipLaunchKernelGGL(prep_w_kernel, dim3(128), dim3(256), 0, stream,
                       Wk, filt, wp3);
    hipLaunchKernelGGL(cnn_enc_kernel, dim3(32 * MT), dim3(256), 0, stream,
                       ub, wp3, bk, out);
}